// Round 9
// baseline (872.857 us; speedup 1.0000x reference)
//
#include <hip/hip_runtime.h>
#include <hip/hip_fp16.h>

typedef _Float16 f16;
typedef _Float16 f16x4 __attribute__((ext_vector_type(4)));
typedef _Float16 f16x8 __attribute__((ext_vector_type(8)));
typedef float    f32x4 __attribute__((ext_vector_type(4)));

#define DEV __device__ __forceinline__

constexpr int B = 32, T = 64, S = 64, H = 512, E = 512, V = 32000;
constexpr int BT = B * T;      // 2048
constexpr int G4 = 4 * H;      // 2048
constexpr int NB2 = 16;        // scan blocks; each owns 32 h-units

DEV float sigf(float x) { return 1.f / (1.f + expf(-x)); }

// relaxed agent-scope ops: compile to plain sc1 loads/stores, NO buffer_wbl2/inv
DEV unsigned long long ld_u64_cg(const unsigned long long* p) {
    return __hip_atomic_load(p, __ATOMIC_RELAXED, __HIP_MEMORY_SCOPE_AGENT);
}
DEV unsigned int ld_u32_cg(const unsigned int* p) {
    return __hip_atomic_load(p, __ATOMIC_RELAXED, __HIP_MEMORY_SCOPE_AGENT);
}
DEV void st_u32_cg(unsigned int* p, unsigned int v) {
    __hip_atomic_store(p, v, __ATOMIC_RELAXED, __HIP_MEMORY_SCOPE_AGENT);
}

// ---------------- converts / packing ----------------

__global__ __launch_bounds__(256) void cvt_f16(const float* __restrict__ s,
                                               f16* __restrict__ d, int n4) {
    for (int i = blockIdx.x * blockDim.x + threadIdx.x; i < n4;
         i += gridDim.x * blockDim.x) {
        float4 v = ((const float4*)s)[i];
        f16x4 o = {(f16)v.x, (f16)v.y, (f16)v.z, (f16)v.w};
        ((f16x4*)d)[i] = o;
    }
}

// Pack W_hh [2048][512] f32 into MFMA B-fragment order, f16.
// Flat n-tile index nt in [0,128): Wf[(nt*16+ks)*64+lane] (8 f16 each) where
// col16 = lane&15, gate-col colg = nt*16+col16, unit = colg>>2, g = colg&3,
// k = ks*32 + (lane>>4)*8 + i, value = W_hh[g*512+unit][k].
__global__ __launch_bounds__(256) void pack_wfrag(const float* __restrict__ W,
                                                  f16* __restrict__ Wf) {
    int id = blockIdx.x * 256 + threadIdx.x;  // 2^17 total
    if (id >= 128 * 16 * 64) return;
    int lane = id & 63;
    int ks = (id >> 6) & 15;
    int nt = id >> 10;
    int colg = nt * 16 + (lane & 15);
    int unit = colg >> 2, g = colg & 3;
    int k = ks * 32 + (lane >> 4) * 8;
    const float* src = W + (size_t)(g * 512 + unit) * 512 + k;
    float4 a = *(const float4*)src;
    float4 b = *(const float4*)(src + 4);
    f16x8 o = {(f16)a.x, (f16)a.y, (f16)a.z, (f16)a.w,
               (f16)b.x, (f16)b.y, (f16)b.z, (f16)b.w};
    *(f16x8*)(Wf + (size_t)id * 8) = o;
}

// x[bt][e] = (f16) emb[tok[bt]][e]
__global__ __launch_bounds__(256) void gather_x(const int* __restrict__ tok,
                                                const float* __restrict__ emb,
                                                f16* __restrict__ x) {
    int id = blockIdx.x * blockDim.x + threadIdx.x;  // 2048*128
    if (id >= BT * (E / 4)) return;
    int row = id >> 7;
    int e4 = (id & 127) * 4;
    int t = tok[row];
    float4 v = *(const float4*)(emb + (size_t)t * E + e4);
    f16x4 o = {(f16)v.x, (f16)v.y, (f16)v.z, (f16)v.w};
    ((f16x4*)x)[id] = o;
}

// stage h0 into xbuf[0] ([n(16)][bb(32)][ul(32)] layout), reset 16 flags
__global__ __launch_bounds__(256) void init_h0(const float* __restrict__ h0,
                                               f16* __restrict__ xbuf,
                                               unsigned int* __restrict__ fl) {
    int i = blockIdx.x * 256 + threadIdx.x;  // 64 blocks -> 16384
    if (i < B * H) {
        int nn = i >> 10;
        int bb = (i >> 5) & 31;
        int ul = i & 31;
        xbuf[i] = (f16)h0[bb * 512 + nn * 32 + ul];
    }
    if (i < NB2) fl[i] = 0u;
}

// ---------------- GEMM: C[M,N] = A[M,K] @ W[N,K]^T (+bias, +tanh) ----------------
// 128x128 tile, BK=32, 256 threads = 4 waves (2x2 of 64x64),
// mfma_f32_16x16x32_f16, reg-staged LDS.
// PERM: write C element (bt, col) to gxp[((t*64+nb)*32 + b)*32 + cl].
// MSWAP: m-tile from blockIdx.x (dispatch-adjacent blocks share the W panel).

template <bool BIAS, bool B2, bool TANH, bool PERM, bool MSWAP, typename OUT>
__global__ __launch_bounds__(256) void gemm_bt(
    const f16* __restrict__ A, int lda, const f16* __restrict__ W, int ldw,
    OUT* __restrict__ C, int ldc, int K, const float* __restrict__ bias1,
    const float* __restrict__ bias2) {
    __shared__ f16 smA[128 * 32];
    __shared__ f16 smB[128 * 32];
    const int tid = threadIdx.x;
    const int lane = tid & 63;
    const int wv = tid >> 6;
    const int wr = wv >> 1, wc = wv & 1;
    const int m0 = (MSWAP ? blockIdx.x : blockIdx.y) * 128;
    const int n0 = (MSWAP ? blockIdx.y : blockIdx.x) * 128;

    const int ar0 = tid >> 2;        // staging row 0..63 (and +64)
    const int kq = (tid & 3) * 8;    // element offset within BK=32

    f32x4 acc[4][4];
#pragma unroll
    for (int m = 0; m < 4; m++)
#pragma unroll
        for (int n = 0; n < 4; n++) acc[m][n] = {0.f, 0.f, 0.f, 0.f};

    const int arow = wr * 64 + (lane & 15);
    const int brow = wc * 64 + (lane & 15);
    const int kk = (lane >> 4) * 8;

    const int ksteps = K >> 5;
    for (int s = 0; s < ksteps; ++s) {
        const int k0 = s * 32;
        const f16* Ag = A + (size_t)(m0 + ar0) * lda + k0 + kq;
        const f16* Wg = W + (size_t)(n0 + ar0) * ldw + k0 + kq;
        uint4 va0 = *(const uint4*)Ag;
        uint4 va1 = *(const uint4*)(Ag + (size_t)64 * lda);
        uint4 vb0 = *(const uint4*)Wg;
        uint4 vb1 = *(const uint4*)(Wg + (size_t)64 * ldw);
        __syncthreads();  // previous compute done -> LDS free
        *(uint4*)(smA + tid * 8) = va0;
        *(uint4*)(smA + (tid + 256) * 8) = va1;
        *(uint4*)(smB + tid * 8) = vb0;
        *(uint4*)(smB + (tid + 256) * 8) = vb1;
        __syncthreads();  // LDS ready
        f16x8 af[4], bfr[4];
#pragma unroll
        for (int m = 0; m < 4; m++)
            af[m] = *(const f16x8*)(smA + (arow + m * 16) * 32 + kk);
#pragma unroll
        for (int n = 0; n < 4; n++)
            bfr[n] = *(const f16x8*)(smB + (brow + n * 16) * 32 + kk);
#pragma unroll
        for (int m = 0; m < 4; m++)
#pragma unroll
            for (int n = 0; n < 4; n++)
                acc[m][n] = __builtin_amdgcn_mfma_f32_16x16x32_f16(
                    af[m], bfr[n], acc[m][n], 0, 0, 0);
    }

    const int fr = lane & 15, fq = lane >> 4;
#pragma unroll
    for (int m = 0; m < 4; m++) {
        const int row0 = m0 + wr * 64 + m * 16 + fq * 4;
#pragma unroll
        for (int n = 0; n < 4; n++) {
            const int col = n0 + wc * 64 + n * 16 + fr;
            float bb = 0.f;
            if (BIAS) bb += bias1[col];
            if (B2) bb += bias2[col];
            int nb = 0, cl = 0;
            if (PERM) {
                int g = col >> 9;
                int unit = col & 511;
                nb = unit >> 3;
                cl = ((unit & 7) << 2) | g;
            }
#pragma unroll
            for (int r = 0; r < 4; r++) {
                float v = acc[m][n][r] + bb;
                if (TANH) v = tanhf(v);
                if (PERM) {
                    int bt = row0 + r;
                    int b_ = bt >> 6, tt = bt & 63;
                    C[((size_t)(tt * 64 + nb) * 32 + b_) * 32 + cl] = (OUT)v;
                } else {
                    C[(size_t)(row0 + r) * ldc + col] = (OUT)v;
                }
            }
        }
    }
}

// ---------------- LSTM scan v8: 16 blocks x 1024 thr, W in LDS -------------
// Block n owns units [n*32, n*32+32) = 128 gate cols = 8 n-tiles; 16 waves =
// 2 m-tiles x 8 n-tiles, 16 MFMA per wave per step (same per-wave work).
// W slice (128KB) staged once into LDS -> frees VGPRs so the 32-u64 h burst
// is fully in flight (1 MALL RTT). xbuf[parity][n][bb][ul]: writer stores
// 2KB contiguous; reader reads 1KB contiguous per (ks,mi). flags[16] in ONE
// cacheline. All-gather traffic 512KB/step (4x less than 64-block version).
// Protocol (proven R5-R7): h stores (sc1) -> vmcnt(0) -> barrier -> flag
// store; reader polls flags then bulk-reads.

__global__ __launch_bounds__(1024, 1) void lstm_scan8(
    const float* __restrict__ gxp, const f16* __restrict__ Wfrag,
    const float* __restrict__ c0, f16* __restrict__ xbuf,
    unsigned int* __restrict__ flags, f16* __restrict__ merged,
    float* __restrict__ hout, float* __restrict__ cout) {
    const int n = blockIdx.x;
    const int tid = threadIdx.x;
    const int lane = tid & 63, wv = tid >> 6;
    const int mi = wv >> 3, ni = wv & 7;
    __shared__ f16 wlds[65536];      // 128KB: block's W_hh slice, frag order
    __shared__ float gl[32][128];    // 16KB: gate exchange

    // stage W slice into LDS once (contiguous 128KB copy)
    {
        const f16* wsrc = Wfrag + (size_t)n * 65536;
#pragma unroll
        for (int i = 0; i < 8; i++)
            *(f16x8*)(wlds + (size_t)(i * 1024 + tid) * 8) =
                *(const f16x8*)(wsrc + (size_t)(i * 1024 + tid) * 8);
    }

    const int bb = tid >> 5, ul = tid & 31;  // (batch, unit-local)
    const int unit = n * 32 + ul;
    float c = c0[bb * 512 + unit];
    float h = 0.f;

    const int fr = lane & 15, fq = lane >> 4;
    const int arow = mi * 16 + fr;
    const int ubase = arow * 8 + fq * 2;     // u64 idx within a ks-group (256)
    const f16* wbase = wlds + (size_t)(ni * 16) * 512 + lane * 8;

    __syncthreads();  // wlds ready

    for (int t = 0; t < T; ++t) {
        // independent prefetch: this thread's 4 gate-x values
        float4 gx4 = *(const float4*)(
            gxp + ((size_t)(t * 64 + n * 4 + (ul >> 3)) * 32 + bb) * 32 +
            (ul & 7) * 4);
        // cheap signal: 16 flags, one cacheline
        for (;;) {
            unsigned int v = ld_u32_cg(flags + (lane & 15));
            if (__all(v >= (unsigned int)t)) break;
            __builtin_amdgcn_s_sleep(1);
        }
        asm volatile("" ::: "memory");  // no load hoisting above the poll
        // full-flight burst: 32 coherent u64 loads -> A-fragments
        const unsigned long long* xb =
            (const unsigned long long*)(xbuf + (t & 1) * (B * H));
        unsigned long long alo[16], ahi[16];
#pragma unroll
        for (int ks = 0; ks < 16; ks++) {
            alo[ks] = ld_u64_cg(xb + ks * 256 + ubase);
            ahi[ks] = ld_u64_cg(xb + ks * 256 + ubase + 1);
        }
        f32x4 acc0 = {0.f, 0.f, 0.f, 0.f}, acc1 = {0.f, 0.f, 0.f, 0.f};
#pragma unroll
        for (int ks = 0; ks < 16; ks++) {
            f16x4 l4 = __builtin_bit_cast(f16x4, alo[ks]);
            f16x4 h4 = __builtin_bit_cast(f16x4, ahi[ks]);
            f16x8 af = {l4.x, l4.y, l4.z, l4.w, h4.x, h4.y, h4.z, h4.w};
            f16x8 bfr = *(const f16x8*)(wbase + ks * 512);
            if (ks & 1)
                acc1 = __builtin_amdgcn_mfma_f32_16x16x32_f16(af, bfr, acc1,
                                                              0, 0, 0);
            else
                acc0 = __builtin_amdgcn_mfma_f32_16x16x32_f16(af, bfr, acc0,
                                                              0, 0, 0);
        }
#pragma unroll
        for (int r = 0; r < 4; r++)
            gl[mi * 16 + fq * 4 + r][ni * 16 + fr] = acc0[r] + acc1[r];
        __syncthreads();
        float4 gv = *(const float4*)&gl[bb][ul * 4];
        float gi = gv.x + gx4.x;
        float gf = gv.y + gx4.y;
        float gg = gv.z + gx4.z;
        float go = gv.w + gx4.w;
        c = sigf(gf) * c + sigf(gi) * tanhf(gg);
        h = sigf(go) * tanhf(c);
        f16 hh = (f16)h;
        // h(t+1) -> other parity: paired lanes -> one u32 sc1 store,
        // block writes 2KB contiguous
        unsigned hv = (unsigned)__builtin_bit_cast(unsigned short, hh);
        unsigned other = (unsigned)__shfl_xor((int)hv, 1);
        f16* xn = xbuf + ((t + 1) & 1) * (B * H);
        if ((ul & 1) == 0)
            st_u32_cg((unsigned int*)(xn + n * 1024 + bb * 32 + ul),
                      hv | (other << 16));
        if (t < T - 1) {
            asm volatile("s_waitcnt vmcnt(0)" ::: "memory");
            __syncthreads();  // all waves drained; also guards gl reuse
            if (tid == 0) st_u32_cg(flags + n, (unsigned int)(t + 1));
        } else {
            __syncthreads();
        }
        // off the critical path (64B contiguous per 32 lanes)
        merged[(size_t)(bb * 64 + t) * 1536 + unit] = hh;
    }
    hout[bb * 512 + unit] = h;
    cout[bb * 512 + unit] = c;
}

// ---------------- fused attention: w = q.enc ; applied = w.enc ----------------

__global__ __launch_bounds__(256) void attn_apply(const float* __restrict__ q,
                                                  const float* __restrict__ enc,
                                                  f16* __restrict__ merged) {
    const int bt = blockIdx.x;
    const int b = bt >> 6;
    const int tid = threadIdx.x;
    __shared__ float qs[1024];
    __shared__ float ws[64];

    const float* qrow = q + (size_t)bt * 1024;
    *(float4*)(qs + tid * 4) = *(const float4*)(qrow + tid * 4);
    __syncthreads();

    const int wv = tid >> 6, lane = tid & 63;
    const float* encb = enc + (size_t)b * S * 1024;
    for (int s = wv * 16; s < wv * 16 + 16; ++s) {
        const float* er = encb + (size_t)s * 1024;
        float p = 0.f;
#pragma unroll
        for (int i = 0; i < 16; ++i) p += qs[lane + 64 * i] * er[lane + 64 * i];
#pragma unroll
        for (int off = 32; off; off >>= 1) p += __shfl_xor(p, off);
        if (lane == 0) ws[s] = p;
    }
    __syncthreads();

    float a0 = 0.f, a1 = 0.f, a2 = 0.f, a3 = 0.f;
    for (int s = 0; s < 64; ++s) {
        float w = ws[s];
        const float* er = encb + (size_t)s * 1024;
        a0 += w * er[tid];
        a1 += w * er[tid + 256];
        a2 += w * er[tid + 512];
        a3 += w * er[tid + 768];
    }
    f16* mrow = merged + (size_t)bt * 1536 + 512;
    mrow[tid] = (f16)a0;
    mrow[tid + 256] = (f16)a1;
    mrow[tid + 512] = (f16)a2;
    mrow[tid + 768] = (f16)a3;
}

// ---------------- launcher ----------------

extern "C" void kernel_launch(void* const* d_in, const int* in_sizes, int n_in,
                              void* d_out, int out_size, void* d_ws,
                              size_t ws_size, hipStream_t stream) {
    const int* tok = (const int*)d_in[0];
    const float* enc = (const float*)d_in[1];
    const float* h0 = (const float*)d_in[2];
    const float* c0 = (const float*)d_in[3];
    const float* emb = (const float*)d_in[4];
    const float* W_ih = (const float*)d_in[5];
    const float* W_hh = (const float*)d_in[6];
    const float* b_ih = (const float*)d_in[7];
    const float* b_hh = (const float*)d_in[8];
    const float* W_att = (const float*)d_in[9];
    const float* W_comb = (const float*)d_in[10];
    const float* b_comb = (const float*)d_in[11];
    const float* W_out = (const float*)d_in[12];
    const float* b_out = (const float*)d_in[13];

    float* out_logits = (float*)d_out;
    float* out_h = out_logits + (size_t)BT * V;
    float* out_c = out_h + (size_t)B * H;

    char* p = (char*)d_ws;
    auto alloc = [&](size_t bytes) -> void* {
        void* r = (void*)p;
        p += (bytes + 255) & ~(size_t)255;
        return r;
    };
    f16* W_ih_h = (f16*)alloc((size_t)G4 * E * 2);
    f16* Wfrag = (f16*)alloc((size_t)128 * 16 * 64 * 8 * 2);  // 2MB
    f16* W_att_h = (f16*)alloc((size_t)1024 * 512 * 2);
    f16* W_comb_h = (f16*)alloc((size_t)512 * 1536 * 2);
    f16* W_out_h = (f16*)alloc((size_t)V * 512 * 2);
    f16* x_h = (f16*)alloc((size_t)BT * E * 2);
    float* gxp = (float*)alloc((size_t)T * 64 * 32 * 32 * 4);  // 16MB
    f16* merged = (f16*)alloc((size_t)BT * 1536 * 2);
    float* qbuf = (float*)alloc((size_t)BT * 1024 * 4);
    f16* outs_h = (f16*)alloc((size_t)BT * 512 * 2);
    f16* xbuf = (f16*)alloc((size_t)2 * B * H * 2);   // exchange
    unsigned int* flags = (unsigned int*)alloc(256);

    cvt_f16<<<512, 256, 0, stream>>>(W_ih, W_ih_h, G4 * E / 4);
    cvt_f16<<<512, 256, 0, stream>>>(W_att, W_att_h, 1024 * 512 / 4);
    cvt_f16<<<512, 256, 0, stream>>>(W_comb, W_comb_h, 512 * 1536 / 4);
    cvt_f16<<<2048, 256, 0, stream>>>(W_out, W_out_h, V * 512 / 4);
    pack_wfrag<<<512, 256, 0, stream>>>(W_hh, Wfrag);
    gather_x<<<1024, 256, 0, stream>>>(tok, emb, x_h);
    init_h0<<<64, 256, 0, stream>>>(h0, xbuf, flags);

    // gates_x = x @ W_ih^T + b_ih + b_hh, written directly in permuted layout
    gemm_bt<true, true, false, true, false, float>
        <<<dim3(16, 16), 256, 0, stream>>>(x_h, E, W_ih_h, E, gxp, 0, E, b_ih,
                                           b_hh);

    // sequential LSTM (16 fat blocks, W in LDS, full-flight burst)
    lstm_scan8<<<NB2, 1024, 0, stream>>>(gxp, Wfrag, c0, xbuf, flags, merged,
                                         out_h, out_c);

    // q = h_all @ W_att^T   [2048 x 1024]  (A = merged cols 0:512, lda=1536)
    gemm_bt<false, false, false, false, false, float>
        <<<dim3(8, 16), 256, 0, stream>>>(merged, 1536, W_att_h, 512, qbuf,
                                          1024, 512, nullptr, nullptr);

    // attention -> merged[:,512:1536]
    attn_apply<<<BT, 256, 0, stream>>>(qbuf, enc, merged);

    // outs = tanh(merged @ W_comb^T + b_comb)   [2048 x 512] f16
    gemm_bt<true, false, true, false, false, f16>
        <<<dim3(4, 16), 256, 0, stream>>>(merged, 1536, W_comb_h, 1536, outs_h,
                                          512, 1536, b_comb, nullptr);

    // logits = outs @ W_out^T + b_out   [2048 x 32000] fp32 -> d_out
    // MSWAP: m-tile on blockIdx.x so dispatch-adjacent blocks share W panel
    gemm_bt<true, false, false, false, true, float>
        <<<dim3(16, 250), 256, 0, stream>>>(outs_h, 512, W_out_h, 512,
                                            out_logits, V, 512, b_out,
                                            nullptr);
}

// Round 10
// 555.275 us; speedup vs baseline: 1.5719x; 1.5719x over previous
//
#include <hip/hip_runtime.h>
#include <hip/hip_fp16.h>

typedef _Float16 f16;
typedef _Float16 f16x4 __attribute__((ext_vector_type(4)));
typedef _Float16 f16x8 __attribute__((ext_vector_type(8)));
typedef float    f32x4 __attribute__((ext_vector_type(4)));

#define DEV __device__ __forceinline__

constexpr int B = 32, T = 64, S = 64, H = 512, E = 512, V = 32000;
constexpr int BT = B * T;      // 2048
constexpr int G4 = 4 * H;      // 2048
constexpr int NBLK = 64;       // scan blocks; each owns 8 h-units

DEV float sigf(float x) { return 1.f / (1.f + expf(-x)); }

#if defined(__has_builtin)
#if __has_builtin(__builtin_amdgcn_global_load_lds)
#define HAVE_GLL 1
#endif
#endif

// relaxed agent-scope ops: compile to plain sc1 loads/stores, NO buffer_wbl2/inv
DEV unsigned long long ld_u64_cg(const unsigned long long* p) {
    return __hip_atomic_load(p, __ATOMIC_RELAXED, __HIP_MEMORY_SCOPE_AGENT);
}
DEV unsigned int ld_u32_cg(const unsigned int* p) {
    return __hip_atomic_load(p, __ATOMIC_RELAXED, __HIP_MEMORY_SCOPE_AGENT);
}
DEV void st_u32_cg(unsigned int* p, unsigned int v) {
    __hip_atomic_store(p, v, __ATOMIC_RELAXED, __HIP_MEMORY_SCOPE_AGENT);
}

#if HAVE_GLL
// async global->LDS, 16B per lane; lds base must be wave-uniform,
// HW scatters lane i to base + i*16.
DEV void gll16(f16* lds, const f16* g) {
    __builtin_amdgcn_global_load_lds(
        (const __attribute__((address_space(1))) void*)g,
        (__attribute__((address_space(3))) void*)lds, 16, 0, 0);
}
#endif

// ---------------- converts / packing ----------------

__global__ __launch_bounds__(256) void cvt_f16(const float* __restrict__ s,
                                               f16* __restrict__ d, int n4) {
    for (int i = blockIdx.x * blockDim.x + threadIdx.x; i < n4;
         i += gridDim.x * blockDim.x) {
        float4 v = ((const float4*)s)[i];
        f16x4 o = {(f16)v.x, (f16)v.y, (f16)v.z, (f16)v.w};
        ((f16x4*)d)[i] = o;
    }
}

// Pack W_hh [2048][512] f32 into MFMA B-fragment order, f16.
// Wf flat index id = ((n*2+ni)*16 + ks)*64 + lane, 8 f16 each:
//   col cl = ni*16 + (lane&15) (block-local gate col, cl = ul*4 + g)
//   k     = ks*32 + (lane>>4)*8 + i
//   value = W_hh[g*512 + (n*8+ul)][k]
__global__ __launch_bounds__(256) void pack_wfrag(const float* __restrict__ W,
                                                  f16* __restrict__ Wf) {
    int id = blockIdx.x * 256 + threadIdx.x;  // 2^17 total
    if (id >= NBLK * 2 * 16 * 64) return;
    int lane = id & 63;
    int ks = (id >> 6) & 15;
    int ni = (id >> 10) & 1;
    int n = id >> 11;
    int cl = ni * 16 + (lane & 15);
    int ul = cl >> 2, g = cl & 3;
    int unit = n * 8 + ul;
    int k = ks * 32 + (lane >> 4) * 8;
    const float* src = W + (size_t)(g * 512 + unit) * 512 + k;
    float4 a = *(const float4*)src;
    float4 b = *(const float4*)(src + 4);
    f16x8 o = {(f16)a.x, (f16)a.y, (f16)a.z, (f16)a.w,
               (f16)b.x, (f16)b.y, (f16)b.z, (f16)b.w};
    *(f16x8*)(Wf + (size_t)id * 8) = o;
}

// x[bt][e] = (f16) emb[tok[bt]][e]
__global__ __launch_bounds__(256) void gather_x(const int* __restrict__ tok,
                                                const float* __restrict__ emb,
                                                f16* __restrict__ x) {
    int id = blockIdx.x * blockDim.x + threadIdx.x;  // 2048*128
    if (id >= BT * (E / 4)) return;
    int row = id >> 7;
    int e4 = (id & 127) * 4;
    int t = tok[row];
    float4 v = *(const float4*)(emb + (size_t)t * E + e4);
    f16x4 o = {(f16)v.x, (f16)v.y, (f16)v.z, (f16)v.w};
    ((f16x4*)x)[id] = o;
}

// stage h0 into xbuf[0] (block-major layout) and reset flags (replay safe)
__global__ __launch_bounds__(256) void init_h0(const float* __restrict__ h0,
                                               f16* __restrict__ xbuf,
                                               unsigned int* __restrict__ fl) {
    int i = blockIdx.x * 256 + threadIdx.x;  // 64 blocks -> 16384
    if (i < B * H) {
        int nn = i >> 8;
        int bb = (i >> 3) & 31;
        int ul = i & 7;
        xbuf[i] = (f16)h0[bb * 512 + nn * 8 + ul];
    }
    if (i < NBLK) fl[i] = 0u;
}

// ---------------- GEMM: C[M,N] = A[M,K] @ W[N,K]^T (+bias, +tanh) ----------------
// 128x128 tile, BK=32, 256 threads = 4 waves (2x2 of 64x64),
// mfma_f32_16x16x32_f16. Staging via global_load_lds width=16 (async DMA,
// no VGPR round-trip); LDS layout smA[tid*8] == wave-uniform base + lane*16.
// PERM: write C element (bt, col) to gxp[((t*64+nb)*32 + b)*32 + cl].
// MSWAP: m-tile from blockIdx.x (dispatch-adjacent blocks share the W panel).

template <bool BIAS, bool B2, bool TANH, bool PERM, bool MSWAP, typename OUT>
__global__ __launch_bounds__(256) void gemm_bt(
    const f16* __restrict__ A, int lda, const f16* __restrict__ W, int ldw,
    OUT* __restrict__ C, int ldc, int K, const float* __restrict__ bias1,
    const float* __restrict__ bias2) {
    __shared__ f16 smA[128 * 32];
    __shared__ f16 smB[128 * 32];
    const int tid = threadIdx.x;
    const int lane = tid & 63;
    const int wv = tid >> 6;
    const int wr = wv >> 1, wc = wv & 1;
    const int m0 = (MSWAP ? blockIdx.x : blockIdx.y) * 128;
    const int n0 = (MSWAP ? blockIdx.y : blockIdx.x) * 128;

    const int ar0 = tid >> 2;        // staging row 0..63 (and +64)
    const int kq = (tid & 3) * 8;    // element offset within BK=32

    f32x4 acc[4][4];
#pragma unroll
    for (int m = 0; m < 4; m++)
#pragma unroll
        for (int n = 0; n < 4; n++) acc[m][n] = {0.f, 0.f, 0.f, 0.f};

    const int arow = wr * 64 + (lane & 15);
    const int brow = wc * 64 + (lane & 15);
    const int kk = (lane >> 4) * 8;

    const int ksteps = K >> 5;
    for (int s = 0; s < ksteps; ++s) {
        const int k0 = s * 32;
        const f16* Ag = A + (size_t)(m0 + ar0) * lda + k0 + kq;
        const f16* Wg = W + (size_t)(n0 + ar0) * ldw + k0 + kq;
#if HAVE_GLL
        __syncthreads();  // previous compute done -> LDS free
        gll16(smA + wv * 512, Ag);
        gll16(smA + 2048 + wv * 512, Ag + (size_t)64 * lda);
        gll16(smB + wv * 512, Wg);
        gll16(smB + 2048 + wv * 512, Wg + (size_t)64 * ldw);
        __syncthreads();  // drains vmcnt -> LDS ready
#else
        uint4 va0 = *(const uint4*)Ag;
        uint4 va1 = *(const uint4*)(Ag + (size_t)64 * lda);
        uint4 vb0 = *(const uint4*)Wg;
        uint4 vb1 = *(const uint4*)(Wg + (size_t)64 * ldw);
        __syncthreads();  // previous compute done -> LDS free
        *(uint4*)(smA + tid * 8) = va0;
        *(uint4*)(smA + (tid + 256) * 8) = va1;
        *(uint4*)(smB + tid * 8) = vb0;
        *(uint4*)(smB + (tid + 256) * 8) = vb1;
        __syncthreads();  // LDS ready
#endif
        f16x8 af[4], bfr[4];
#pragma unroll
        for (int m = 0; m < 4; m++)
            af[m] = *(const f16x8*)(smA + (arow + m * 16) * 32 + kk);
#pragma unroll
        for (int n = 0; n < 4; n++)
            bfr[n] = *(const f16x8*)(smB + (brow + n * 16) * 32 + kk);
#pragma unroll
        for (int m = 0; m < 4; m++)
#pragma unroll
            for (int n = 0; n < 4; n++)
                acc[m][n] = __builtin_amdgcn_mfma_f32_16x16x32_f16(
                    af[m], bfr[n], acc[m][n], 0, 0, 0);
    }

    const int fr = lane & 15, fq = lane >> 4;
#pragma unroll
    for (int m = 0; m < 4; m++) {
        const int row0 = m0 + wr * 64 + m * 16 + fq * 4;
#pragma unroll
        for (int n = 0; n < 4; n++) {
            const int col = n0 + wc * 64 + n * 16 + fr;
            float bb = 0.f;
            if (BIAS) bb += bias1[col];
            if (B2) bb += bias2[col];
            int nb = 0, cl = 0;
            if (PERM) {
                int g = col >> 9;
                int unit = col & 511;
                nb = unit >> 3;
                cl = ((unit & 7) << 2) | g;
            }
#pragma unroll
            for (int r = 0; r < 4; r++) {
                float v = acc[m][n][r] + bb;
                if (TANH) v = tanhf(v);
                if (PERM) {
                    int bt = row0 + r;
                    int b_ = bt >> 6, tt = bt & 63;
                    C[((size_t)(tt * 64 + nb) * 32 + b_) * 32 + cl] = (OUT)v;
                } else {
                    C[(size_t)(row0 + r) * ldc + col] = (OUT)v;
                }
            }
        }
    }
}

// ---------------- persistent-W LSTM scan (R6 structure, measured best) -----
// 64 blocks x 256 threads. Block n owns h-units [n*8, n*8+8).
// xbuf[2][64 n][32 bb][8 ul] f16: block-major exchange buffer.
// flags[64]: flag[n]=t means block n published h(t) into xbuf[t&1].
// Reader: poll 64 flags (1 load/lane), then ONE cooperative burst read:
// each thread 16 coalesced sc1 u64 loads (all in flight, one MALL RTT)
// -> LDS hst[32][520] -> MFMA frags.
// Writer: h stores (sc1) -> vmcnt(0) -> syncthreads -> flag store.

__global__ __launch_bounds__(256, 1) void lstm_scan6(
    const float* __restrict__ gxp, const f16* __restrict__ Wfrag,
    const float* __restrict__ c0, f16* __restrict__ xbuf,
    unsigned int* __restrict__ flags, f16* __restrict__ merged,
    float* __restrict__ hout, float* __restrict__ cout) {
    const int n = blockIdx.x;
    const int tid = threadIdx.x;
    const int lane = tid & 63, wv = tid >> 6;
    const int mi = wv >> 1, ni = wv & 1;
    __shared__ f16 hst[32][520];    // staged h, +8 f16 row pad
    __shared__ float gl[32][32];

    // persistent B-fragments (the block's W_hh slice)
    f16x8 bf[16];
    const f16* wbase = Wfrag + (size_t)((n * 2 + ni) * 16) * 512 + lane * 8;
#pragma unroll
    for (int ks = 0; ks < 16; ks++) bf[ks] = *(const f16x8*)(wbase + ks * 512);

    const int bb = tid >> 3, ul = tid & 7;   // (batch, unit-local)
    const int unit = n * 8 + ul;
    float c = c0[bb * 512 + unit];
    float h = 0.f;

    // staging decomposition: u64 word w = i*256+tid covers f16 idx 4w ->
    // n' = i*4 + wv, sb = (tid&63)>>1, su0 = (tid&1)*4
    const int sb = (tid & 63) >> 1;
    const int su0 = (tid & 1) * 4;

    const int arow = mi * 16 + (lane & 15);
    const int kcol0 = (lane >> 4) * 8;
    const int fr = lane & 15, fq = lane >> 4;

    for (int t = 0; t < T; ++t) {
        // independent prefetch: this thread's 4 gate-x values (coalesced)
        float4 gx4 = *(const float4*)(gxp +
                                      ((size_t)(t * NBLK + n) * 32 + bb) * 32 +
                                      ul * 4);
        // cheap signal: all 64 producer flags >= t
        for (;;) {
            unsigned int v = ld_u32_cg(flags + lane);
            if (__all(v >= (unsigned int)t)) break;
            __builtin_amdgcn_s_sleep(1);
        }
        asm volatile("" ::: "memory");  // no load hoisting above the poll
        // cooperative burst: 16 coalesced sc1 u64 loads, all outstanding
        const unsigned long long* src =
            (const unsigned long long*)(xbuf + (t & 1) * (B * H));
        unsigned long long v[16];
#pragma unroll
        for (int i = 0; i < 16; i++) v[i] = ld_u64_cg(src + i * 256 + tid);
#pragma unroll
        for (int i = 0; i < 16; i++) {
            int np = i * 4 + wv;
            *(unsigned long long*)(&hst[sb][np * 8 + su0]) = v[i];
        }
        __syncthreads();
        // A-frags from LDS + 16 MFMA (2 chains)
        f32x4 acc0 = {0.f, 0.f, 0.f, 0.f}, acc1 = {0.f, 0.f, 0.f, 0.f};
#pragma unroll
        for (int ks = 0; ks < 16; ks++) {
            f16x8 af = *(const f16x8*)(&hst[arow][ks * 32 + kcol0]);
            if (ks & 1)
                acc1 = __builtin_amdgcn_mfma_f32_16x16x32_f16(af, bf[ks], acc1,
                                                              0, 0, 0);
            else
                acc0 = __builtin_amdgcn_mfma_f32_16x16x32_f16(af, bf[ks], acc0,
                                                              0, 0, 0);
        }
#pragma unroll
        for (int r = 0; r < 4; r++)
            gl[mi * 16 + fq * 4 + r][ni * 16 + fr] = acc0[r] + acc1[r];
        __syncthreads();
        float4 gv = *(const float4*)&gl[bb][ul * 4];
        float gi = gv.x + gx4.x;
        float gf = gv.y + gx4.y;
        float gg = gv.z + gx4.z;
        float go = gv.w + gx4.w;
        c = sigf(gf) * c + sigf(gi) * tanhf(gg);
        h = sigf(go) * tanhf(c);
        f16 hh = (f16)h;
        // h(t+1) -> other parity, block-major: paired lanes -> one u32 store
        unsigned hv = (unsigned)__builtin_bit_cast(unsigned short, hh);
        unsigned other = (unsigned)__shfl_xor((int)hv, 1);
        f16* xn = xbuf + ((t + 1) & 1) * (B * H);
        if ((ul & 1) == 0) {
            st_u32_cg((unsigned int*)(xn + n * 256 + bb * 8 + ul),
                      hv | (other << 16));
        }
        if (t < T - 1) {
            asm volatile("s_waitcnt vmcnt(0)" ::: "memory");
            __syncthreads();  // all waves' h-stores at the coherence point
            if (tid == 0) st_u32_cg(flags + n, (unsigned int)(t + 1));
        } else {
            __syncthreads();
        }
        // off the critical path
        merged[(size_t)(bb * 64 + t) * 1536 + unit] = hh;
    }
    hout[bb * 512 + unit] = h;
    cout[bb * 512 + unit] = c;
}

// ---------------- fused attention: w = q.enc ; applied = w.enc ----------------

__global__ __launch_bounds__(256) void attn_apply(const float* __restrict__ q,
                                                  const float* __restrict__ enc,
                                                  f16* __restrict__ merged) {
    const int bt = blockIdx.x;
    const int b = bt >> 6;
    const int tid = threadIdx.x;
    __shared__ float qs[1024];
    __shared__ float ws[64];

    const float* qrow = q + (size_t)bt * 1024;
    *(float4*)(qs + tid * 4) = *(const float4*)(qrow + tid * 4);
    __syncthreads();

    const int wv = tid >> 6, lane = tid & 63;
    const float* encb = enc + (size_t)b * S * 1024;
    for (int s = wv * 16; s < wv * 16 + 16; ++s) {
        const float* er = encb + (size_t)s * 1024;
        float p = 0.f;
#pragma unroll
        for (int i = 0; i < 16; ++i) p += qs[lane + 64 * i] * er[lane + 64 * i];
#pragma unroll
        for (int off = 32; off; off >>= 1) p += __shfl_xor(p, off);
        if (lane == 0) ws[s] = p;
    }
    __syncthreads();

    float a0 = 0.f, a1 = 0.f, a2 = 0.f, a3 = 0.f;
    for (int s = 0; s < 64; ++s) {
        float w = ws[s];
        const float* er = encb + (size_t)s * 1024;
        a0 += w * er[tid];
        a1 += w * er[tid + 256];
        a2 += w * er[tid + 512];
        a3 += w * er[tid + 768];
    }
    f16* mrow = merged + (size_t)bt * 1536 + 512;
    mrow[tid] = (f16)a0;
    mrow[tid + 256] = (f16)a1;
    mrow[tid + 512] = (f16)a2;
    mrow[tid + 768] = (f16)a3;
}

// ---------------- launcher ----------------

extern "C" void kernel_launch(void* const* d_in, const int* in_sizes, int n_in,
                              void* d_out, int out_size, void* d_ws,
                              size_t ws_size, hipStream_t stream) {
    const int* tok = (const int*)d_in[0];
    const float* enc = (const float*)d_in[1];
    const float* h0 = (const float*)d_in[2];
    const float* c0 = (const float*)d_in[3];
    const float* emb = (const float*)d_in[4];
    const float* W_ih = (const float*)d_in[5];
    const float* W_hh = (const float*)d_in[6];
    const float* b_ih = (const float*)d_in[7];
    const float* b_hh = (const float*)d_in[8];
    const float* W_att = (const float*)d_in[9];
    const float* W_comb = (const float*)d_in[10];
    const float* b_comb = (const float*)d_in[11];
    const float* W_out = (const float*)d_in[12];
    const float* b_out = (const float*)d_in[13];

    float* out_logits = (float*)d_out;
    float* out_h = out_logits + (size_t)BT * V;
    float* out_c = out_h + (size_t)B * H;

    char* p = (char*)d_ws;
    auto alloc = [&](size_t bytes) -> void* {
        void* r = (void*)p;
        p += (bytes + 255) & ~(size_t)255;
        return r;
    };
    f16* W_ih_h = (f16*)alloc((size_t)G4 * E * 2);
    f16* Wfrag = (f16*)alloc((size_t)NBLK * 2 * 16 * 64 * 8 * 2);  // 2MB
    f16* W_att_h = (f16*)alloc((size_t)1024 * 512 * 2);
    f16* W_comb_h = (f16*)alloc((size_t)512 * 1536 * 2);
    f16* W_out_h = (f16*)alloc((size_t)V * 512 * 2);
    f16* x_h = (f16*)alloc((size_t)BT * E * 2);
    float* gxp = (float*)alloc((size_t)T * NBLK * 32 * 32 * 4);  // 16MB
    f16* merged = (f16*)alloc((size_t)BT * 1536 * 2);
    float* qbuf = (float*)alloc((size_t)BT * 1024 * 4);
    f16* outs_h = (f16*)alloc((size_t)BT * 512 * 2);
    f16* xbuf = (f16*)alloc((size_t)2 * B * H * 2);   // exchange, block-major
    unsigned int* flags = (unsigned int*)alloc(256);

    cvt_f16<<<512, 256, 0, stream>>>(W_ih, W_ih_h, G4 * E / 4);
    cvt_f16<<<512, 256, 0, stream>>>(W_att, W_att_h, 1024 * 512 / 4);
    cvt_f16<<<512, 256, 0, stream>>>(W_comb, W_comb_h, 512 * 1536 / 4);
    cvt_f16<<<2048, 256, 0, stream>>>(W_out, W_out_h, V * 512 / 4);
    pack_wfrag<<<512, 256, 0, stream>>>(W_hh, Wfrag);
    gather_x<<<1024, 256, 0, stream>>>(tok, emb, x_h);
    init_h0<<<64, 256, 0, stream>>>(h0, xbuf, flags);

    // gates_x = x @ W_ih^T + b_ih + b_hh, written directly in permuted layout
    gemm_bt<true, true, false, true, false, float>
        <<<dim3(16, 16), 256, 0, stream>>>(x_h, E, W_ih_h, E, gxp, 0, E, b_ih,
                                           b_hh);

    // sequential LSTM (R6 structure: persistent W, flag signal + staged read)
    lstm_scan6<<<NBLK, 256, 0, stream>>>(gxp, Wfrag, c0, xbuf, flags, merged,
                                         out_h, out_c);

    // q = h_all @ W_att^T   [2048 x 1024]  (A = merged cols 0:512, lda=1536)
    gemm_bt<false, false, false, false, false, float>
        <<<dim3(8, 16), 256, 0, stream>>>(merged, 1536, W_att_h, 512, qbuf,
                                          1024, 512, nullptr, nullptr);

    // attention -> merged[:,512:1536]
    attn_apply<<<BT, 256, 0, stream>>>(qbuf, enc, merged);

    // outs = tanh(merged @ W_comb^T + b_comb)   [2048 x 512] f16
    gemm_bt<true, false, true, false, false, f16>
        <<<dim3(4, 16), 256, 0, stream>>>(merged, 1536, W_comb_h, 1536, outs_h,
                                          512, 1536, b_comb, nullptr);

    // logits = outs @ W_out^T + b_out   [2048 x 32000] fp32 -> d_out
    // MSWAP: m-tile on blockIdx.x so dispatch-adjacent blocks share W panel
    gemm_bt<true, false, false, false, true, float>
        <<<dim3(16, 250), 256, 0, stream>>>(outs_h, 512, W_out_h, 512,
                                            out_logits, V, 512, b_out,
                                            nullptr);
}

// Round 11
// 525.288 us; speedup vs baseline: 1.6617x; 1.0571x over previous
//
#include <hip/hip_runtime.h>
#include <hip/hip_fp16.h>

typedef _Float16 f16;
typedef _Float16 f16x4 __attribute__((ext_vector_type(4)));
typedef _Float16 f16x8 __attribute__((ext_vector_type(8)));
typedef float    f32x4 __attribute__((ext_vector_type(4)));

#define DEV __device__ __forceinline__

constexpr int B = 32, T = 64, S = 64, H = 512, E = 512, V = 32000;
constexpr int BT = B * T;      // 2048
constexpr int G4 = 4 * H;      // 2048
constexpr int NBLK = 64;       // scan blocks; each owns 8 h-units

DEV float sigf(float x) { return 1.f / (1.f + expf(-x)); }

#if defined(__has_builtin)
#if __has_builtin(__builtin_amdgcn_global_load_lds)
#define HAVE_GLL 1
#endif
#endif

// relaxed agent-scope ops: compile to plain sc1 loads/stores, NO buffer_wbl2/inv
DEV unsigned long long ld_u64_cg(const unsigned long long* p) {
    return __hip_atomic_load(p, __ATOMIC_RELAXED, __HIP_MEMORY_SCOPE_AGENT);
}
DEV unsigned int ld_u32_cg(const unsigned int* p) {
    return __hip_atomic_load(p, __ATOMIC_RELAXED, __HIP_MEMORY_SCOPE_AGENT);
}
DEV void st_u32_cg(unsigned int* p, unsigned int v) {
    __hip_atomic_store(p, v, __ATOMIC_RELAXED, __HIP_MEMORY_SCOPE_AGENT);
}

#if HAVE_GLL
// async global->LDS, 16B per lane; lds base must be wave-uniform,
// HW scatters lane i to base + i*16.
DEV void gll16(f16* lds, const f16* g) {
    __builtin_amdgcn_global_load_lds(
        (const __attribute__((address_space(1))) void*)g,
        (__attribute__((address_space(3))) void*)lds, 16, 0, 0);
}
#endif

// ---------------- converts / packing ----------------

__global__ __launch_bounds__(256) void cvt_f16(const float* __restrict__ s,
                                               f16* __restrict__ d, int n4) {
    for (int i = blockIdx.x * blockDim.x + threadIdx.x; i < n4;
         i += gridDim.x * blockDim.x) {
        float4 v = ((const float4*)s)[i];
        f16x4 o = {(f16)v.x, (f16)v.y, (f16)v.z, (f16)v.w};
        ((f16x4*)d)[i] = o;
    }
}

// Pack W_hh [2048][512] f32 into MFMA B-fragment order, f16.
// Wf flat index id = ((n*2+ni)*16 + ks)*64 + lane, 8 f16 each:
//   col cl = ni*16 + (lane&15) (block-local gate col, cl = ul*4 + g)
//   k     = ks*32 + (lane>>4)*8 + i
//   value = W_hh[g*512 + (n*8+ul)][k]
__global__ __launch_bounds__(256) void pack_wfrag(const float* __restrict__ W,
                                                  f16* __restrict__ Wf) {
    int id = blockIdx.x * 256 + threadIdx.x;  // 2^17 total
    if (id >= NBLK * 2 * 16 * 64) return;
    int lane = id & 63;
    int ks = (id >> 6) & 15;
    int ni = (id >> 10) & 1;
    int n = id >> 11;
    int cl = ni * 16 + (lane & 15);
    int ul = cl >> 2, g = cl & 3;
    int unit = n * 8 + ul;
    int k = ks * 32 + (lane >> 4) * 8;
    const float* src = W + (size_t)(g * 512 + unit) * 512 + k;
    float4 a = *(const float4*)src;
    float4 b = *(const float4*)(src + 4);
    f16x8 o = {(f16)a.x, (f16)a.y, (f16)a.z, (f16)a.w,
               (f16)b.x, (f16)b.y, (f16)b.z, (f16)b.w};
    *(f16x8*)(Wf + (size_t)id * 8) = o;
}

// x[bt][e] = (f16) emb[tok[bt]][e]
__global__ __launch_bounds__(256) void gather_x(const int* __restrict__ tok,
                                                const float* __restrict__ emb,
                                                f16* __restrict__ x) {
    int id = blockIdx.x * blockDim.x + threadIdx.x;  // 2048*128
    if (id >= BT * (E / 4)) return;
    int row = id >> 7;
    int e4 = (id & 127) * 4;
    int t = tok[row];
    float4 v = *(const float4*)(emb + (size_t)t * E + e4);
    f16x4 o = {(f16)v.x, (f16)v.y, (f16)v.z, (f16)v.w};
    ((f16x4*)x)[id] = o;
}

// stage h0 into xbuf[0] (block-major layout) and reset flags (replay safe)
__global__ __launch_bounds__(256) void init_h0(const float* __restrict__ h0,
                                               f16* __restrict__ xbuf,
                                               unsigned int* __restrict__ fl) {
    int i = blockIdx.x * 256 + threadIdx.x;  // 64 blocks -> 16384
    if (i < B * H) {
        int nn = i >> 8;
        int bb = (i >> 3) & 31;
        int ul = i & 7;
        xbuf[i] = (f16)h0[bb * 512 + nn * 8 + ul];
    }
    if (i < NBLK) fl[i] = 0u;
}

// ---------------- GEMM: C[M,N] = A[M,K] @ W[N,K]^T (+bias, +tanh) ----------------
// 128x128 tile, BK=32, 256 threads = 4 waves (2x2 of 64x64),
// mfma_f32_16x16x32_f16. Staging via global_load_lds width=16 (async DMA,
// no VGPR round-trip); LDS layout smA[tid*8] == wave-uniform base + lane*16.
// PERM: write C element (bt, col) to gxp[((t*64+nb)*32 + b)*32 + cl].
// MSWAP: m-tile from blockIdx.x (dispatch-adjacent blocks share the W panel).

template <bool BIAS, bool B2, bool TANH, bool PERM, bool MSWAP, typename OUT>
__global__ __launch_bounds__(256) void gemm_bt(
    const f16* __restrict__ A, int lda, const f16* __restrict__ W, int ldw,
    OUT* __restrict__ C, int ldc, int K, const float* __restrict__ bias1,
    const float* __restrict__ bias2) {
    __shared__ f16 smA[128 * 32];
    __shared__ f16 smB[128 * 32];
    const int tid = threadIdx.x;
    const int lane = tid & 63;
    const int wv = tid >> 6;
    const int wr = wv >> 1, wc = wv & 1;
    const int m0 = (MSWAP ? blockIdx.x : blockIdx.y) * 128;
    const int n0 = (MSWAP ? blockIdx.y : blockIdx.x) * 128;

    const int ar0 = tid >> 2;        // staging row 0..63 (and +64)
    const int kq = (tid & 3) * 8;    // element offset within BK=32

    f32x4 acc[4][4];
#pragma unroll
    for (int m = 0; m < 4; m++)
#pragma unroll
        for (int n = 0; n < 4; n++) acc[m][n] = {0.f, 0.f, 0.f, 0.f};

    const int arow = wr * 64 + (lane & 15);
    const int brow = wc * 64 + (lane & 15);
    const int kk = (lane >> 4) * 8;

    const int ksteps = K >> 5;
    for (int s = 0; s < ksteps; ++s) {
        const int k0 = s * 32;
        const f16* Ag = A + (size_t)(m0 + ar0) * lda + k0 + kq;
        const f16* Wg = W + (size_t)(n0 + ar0) * ldw + k0 + kq;
#if HAVE_GLL
        __syncthreads();  // previous compute done -> LDS free
        gll16(smA + wv * 512, Ag);
        gll16(smA + 2048 + wv * 512, Ag + (size_t)64 * lda);
        gll16(smB + wv * 512, Wg);
        gll16(smB + 2048 + wv * 512, Wg + (size_t)64 * ldw);
        __syncthreads();  // drains vmcnt -> LDS ready
#else
        uint4 va0 = *(const uint4*)Ag;
        uint4 va1 = *(const uint4*)(Ag + (size_t)64 * lda);
        uint4 vb0 = *(const uint4*)Wg;
        uint4 vb1 = *(const uint4*)(Wg + (size_t)64 * ldw);
        __syncthreads();  // previous compute done -> LDS free
        *(uint4*)(smA + tid * 8) = va0;
        *(uint4*)(smA + (tid + 256) * 8) = va1;
        *(uint4*)(smB + tid * 8) = vb0;
        *(uint4*)(smB + (tid + 256) * 8) = vb1;
        __syncthreads();  // LDS ready
#endif
        f16x8 af[4], bfr[4];
#pragma unroll
        for (int m = 0; m < 4; m++)
            af[m] = *(const f16x8*)(smA + (arow + m * 16) * 32 + kk);
#pragma unroll
        for (int n = 0; n < 4; n++)
            bfr[n] = *(const f16x8*)(smB + (brow + n * 16) * 32 + kk);
#pragma unroll
        for (int m = 0; m < 4; m++)
#pragma unroll
            for (int n = 0; n < 4; n++)
                acc[m][n] = __builtin_amdgcn_mfma_f32_16x16x32_f16(
                    af[m], bfr[n], acc[m][n], 0, 0, 0);
    }

    const int fr = lane & 15, fq = lane >> 4;
#pragma unroll
    for (int m = 0; m < 4; m++) {
        const int row0 = m0 + wr * 64 + m * 16 + fq * 4;
#pragma unroll
        for (int n = 0; n < 4; n++) {
            const int col = n0 + wc * 64 + n * 16 + fr;
            float bb = 0.f;
            if (BIAS) bb += bias1[col];
            if (B2) bb += bias2[col];
            int nb = 0, cl = 0;
            if (PERM) {
                int g = col >> 9;
                int unit = col & 511;
                nb = unit >> 3;
                cl = ((unit & 7) << 2) | g;
            }
#pragma unroll
            for (int r = 0; r < 4; r++) {
                float v = acc[m][n][r] + bb;
                if (TANH) v = tanhf(v);
                if (PERM) {
                    int bt = row0 + r;
                    int b_ = bt >> 6, tt = bt & 63;
                    C[((size_t)(tt * 64 + nb) * 32 + b_) * 32 + cl] = (OUT)v;
                } else {
                    C[(size_t)(row0 + r) * ldc + col] = (OUT)v;
                }
            }
        }
    }
}

// ---------------- persistent-W LSTM scan (R6 structure, measured best) -----
// 64 blocks x 256 threads. Block n owns h-units [n*8, n*8+8).
// xbuf[2][64 n][32 bb][8 ul] f16: block-major exchange buffer.
// flags[64]: flag[n]=t means block n published h(t) into xbuf[t&1].
// Reader: poll 64 flags (1 load/lane), then ONE cooperative burst read:
// each thread 16 coalesced sc1 u64 loads (all in flight, one MALL RTT)
// -> LDS hst[32][520] -> MFMA frags.
// Writer: h stores (sc1) -> vmcnt(0) -> syncthreads -> flag store.

__global__ __launch_bounds__(256, 1) void lstm_scan6(
    const float* __restrict__ gxp, const f16* __restrict__ Wfrag,
    const float* __restrict__ c0, f16* __restrict__ xbuf,
    unsigned int* __restrict__ flags, f16* __restrict__ merged,
    float* __restrict__ hout, float* __restrict__ cout) {
    const int n = blockIdx.x;
    const int tid = threadIdx.x;
    const int lane = tid & 63, wv = tid >> 6;
    const int mi = wv >> 1, ni = wv & 1;
    __shared__ f16 hst[32][520];    // staged h, +8 f16 row pad
    __shared__ float gl[32][32];

    // persistent B-fragments (the block's W_hh slice)
    f16x8 bf[16];
    const f16* wbase = Wfrag + (size_t)((n * 2 + ni) * 16) * 512 + lane * 8;
#pragma unroll
    for (int ks = 0; ks < 16; ks++) bf[ks] = *(const f16x8*)(wbase + ks * 512);

    const int bb = tid >> 3, ul = tid & 7;   // (batch, unit-local)
    const int unit = n * 8 + ul;
    float c = c0[bb * 512 + unit];
    float h = 0.f;

    // staging decomposition: u64 word w = i*256+tid covers f16 idx 4w ->
    // n' = i*4 + wv, sb = (tid&63)>>1, su0 = (tid&1)*4
    const int sb = (tid & 63) >> 1;
    const int su0 = (tid & 1) * 4;

    const int arow = mi * 16 + (lane & 15);
    const int kcol0 = (lane >> 4) * 8;
    const int fr = lane & 15, fq = lane >> 4;

    for (int t = 0; t < T; ++t) {
        // independent prefetch: this thread's 4 gate-x values (coalesced)
        float4 gx4 = *(const float4*)(gxp +
                                      ((size_t)(t * NBLK + n) * 32 + bb) * 32 +
                                      ul * 4);
        // cheap signal: all 64 producer flags >= t
        for (;;) {
            unsigned int v = ld_u32_cg(flags + lane);
            if (__all(v >= (unsigned int)t)) break;
            __builtin_amdgcn_s_sleep(1);
        }
        asm volatile("" ::: "memory");  // no load hoisting above the poll
        // cooperative burst: 16 coalesced sc1 u64 loads, all outstanding
        const unsigned long long* src =
            (const unsigned long long*)(xbuf + (t & 1) * (B * H));
        unsigned long long v[16];
#pragma unroll
        for (int i = 0; i < 16; i++) v[i] = ld_u64_cg(src + i * 256 + tid);
#pragma unroll
        for (int i = 0; i < 16; i++) {
            int np = i * 4 + wv;
            *(unsigned long long*)(&hst[sb][np * 8 + su0]) = v[i];
        }
        __syncthreads();
        // A-frags from LDS + 16 MFMA (2 chains)
        f32x4 acc0 = {0.f, 0.f, 0.f, 0.f}, acc1 = {0.f, 0.f, 0.f, 0.f};
#pragma unroll
        for (int ks = 0; ks < 16; ks++) {
            f16x8 af = *(const f16x8*)(&hst[arow][ks * 32 + kcol0]);
            if (ks & 1)
                acc1 = __builtin_amdgcn_mfma_f32_16x16x32_f16(af, bf[ks], acc1,
                                                              0, 0, 0);
            else
                acc0 = __builtin_amdgcn_mfma_f32_16x16x32_f16(af, bf[ks], acc0,
                                                              0, 0, 0);
        }
#pragma unroll
        for (int r = 0; r < 4; r++)
            gl[mi * 16 + fq * 4 + r][ni * 16 + fr] = acc0[r] + acc1[r];
        __syncthreads();
        float4 gv = *(const float4*)&gl[bb][ul * 4];
        float gi = gv.x + gx4.x;
        float gf = gv.y + gx4.y;
        float gg = gv.z + gx4.z;
        float go = gv.w + gx4.w;
        c = sigf(gf) * c + sigf(gi) * tanhf(gg);
        h = sigf(go) * tanhf(c);
        f16 hh = (f16)h;
        // h(t+1) -> other parity, block-major: paired lanes -> one u32 store
        unsigned hv = (unsigned)__builtin_bit_cast(unsigned short, hh);
        unsigned other = (unsigned)__shfl_xor((int)hv, 1);
        f16* xn = xbuf + ((t + 1) & 1) * (B * H);
        if ((ul & 1) == 0) {
            st_u32_cg((unsigned int*)(xn + n * 256 + bb * 8 + ul),
                      hv | (other << 16));
        }
        if (t < T - 1) {
            asm volatile("s_waitcnt vmcnt(0)" ::: "memory");
            __syncthreads();  // all waves' h-stores at the coherence point
            if (tid == 0) st_u32_cg(flags + n, (unsigned int)(t + 1));
        } else {
            __syncthreads();
        }
        // off the critical path
        merged[(size_t)(bb * 64 + t) * 1536 + unit] = hh;
    }
    hout[bb * 512 + unit] = h;
    cout[bb * 512 + unit] = c;
}

// ---------------- fused attention: w = q.enc ; applied = w.enc ----------------

__global__ __launch_bounds__(256) void attn_apply(const float* __restrict__ q,
                                                  const float* __restrict__ enc,
                                                  f16* __restrict__ merged) {
    const int bt = blockIdx.x;
    const int b = bt >> 6;
    const int tid = threadIdx.x;
    __shared__ float qs[1024];
    __shared__ float ws[64];

    const float* qrow = q + (size_t)bt * 1024;
    *(float4*)(qs + tid * 4) = *(const float4*)(qrow + tid * 4);
    __syncthreads();

    const int wv = tid >> 6, lane = tid & 63;
    const float* encb = enc + (size_t)b * S * 1024;
    for (int s = wv * 16; s < wv * 16 + 16; ++s) {
        const float* er = encb + (size_t)s * 1024;
        float p = 0.f;
#pragma unroll
        for (int i = 0; i < 16; ++i) p += qs[lane + 64 * i] * er[lane + 64 * i];
#pragma unroll
        for (int off = 32; off; off >>= 1) p += __shfl_xor(p, off);
        if (lane == 0) ws[s] = p;
    }
    __syncthreads();

    float a0 = 0.f, a1 = 0.f, a2 = 0.f, a3 = 0.f;
    for (int s = 0; s < 64; ++s) {
        float w = ws[s];
        const float* er = encb + (size_t)s * 1024;
        a0 += w * er[tid];
        a1 += w * er[tid + 256];
        a2 += w * er[tid + 512];
        a3 += w * er[tid + 768];
    }
    f16* mrow = merged + (size_t)bt * 1536 + 512;
    mrow[tid] = (f16)a0;
    mrow[tid + 256] = (f16)a1;
    mrow[tid + 512] = (f16)a2;
    mrow[tid + 768] = (f16)a3;
}

// ---------------- launcher ----------------

extern "C" void kernel_launch(void* const* d_in, const int* in_sizes, int n_in,
                              void* d_out, int out_size, void* d_ws,
                              size_t ws_size, hipStream_t stream) {
    const int* tok = (const int*)d_in[0];
    const float* enc = (const float*)d_in[1];
    const float* h0 = (const float*)d_in[2];
    const float* c0 = (const float*)d_in[3];
    const float* emb = (const float*)d_in[4];
    const float* W_ih = (const float*)d_in[5];
    const float* W_hh = (const float*)d_in[6];
    const float* b_ih = (const float*)d_in[7];
    const float* b_hh = (const float*)d_in[8];
    const float* W_att = (const float*)d_in[9];
    const float* W_comb = (const float*)d_in[10];
    const float* b_comb = (const float*)d_in[11];
    const float* W_out = (const float*)d_in[12];
    const float* b_out = (const float*)d_in[13];

    float* out_logits = (float*)d_out;
    float* out_h = out_logits + (size_t)BT * V;
    float* out_c = out_h + (size_t)B * H;

    char* p = (char*)d_ws;
    auto alloc = [&](size_t bytes) -> void* {
        void* r = (void*)p;
        p += (bytes + 255) & ~(size_t)255;
        return r;
    };
    f16* W_ih_h = (f16*)alloc((size_t)G4 * E * 2);
    f16* Wfrag = (f16*)alloc((size_t)NBLK * 2 * 16 * 64 * 8 * 2);  // 2MB
    f16* W_att_h = (f16*)alloc((size_t)1024 * 512 * 2);
    f16* W_comb_h = (f16*)alloc((size_t)512 * 1536 * 2);
    f16* W_out_h = (f16*)alloc((size_t)V * 512 * 2);
    f16* x_h = (f16*)alloc((size_t)BT * E * 2);
    float* gxp = (float*)alloc((size_t)T * NBLK * 32 * 32 * 4);  // 16MB
    f16* merged = (f16*)alloc((size_t)BT * 1536 * 2);
    float* qbuf = (float*)alloc((size_t)BT * 1024 * 4);
    f16* outs_h = (f16*)alloc((size_t)BT * 512 * 2);
    f16* xbuf = (f16*)alloc((size_t)2 * B * H * 2);   // exchange, block-major
    unsigned int* flags = (unsigned int*)alloc(256);

    cvt_f16<<<512, 256, 0, stream>>>(W_ih, W_ih_h, G4 * E / 4);
    cvt_f16<<<512, 256, 0, stream>>>(W_att, W_att_h, 1024 * 512 / 4);
    cvt_f16<<<512, 256, 0, stream>>>(W_comb, W_comb_h, 512 * 1536 / 4);
    cvt_f16<<<2048, 256, 0, stream>>>(W_out, W_out_h, V * 512 / 4);
    pack_wfrag<<<512, 256, 0, stream>>>(W_hh, Wfrag);
    gather_x<<<1024, 256, 0, stream>>>(tok, emb, x_h);
    init_h0<<<64, 256, 0, stream>>>(h0, xbuf, flags);

    // gates_x = x @ W_ih^T + b_ih + b_hh, written directly in permuted layout
    gemm_bt<true, true, false, true, false, float>
        <<<dim3(16, 16), 256, 0, stream>>>(x_h, E, W_ih_h, E, gxp, 0, E, b_ih,
                                           b_hh);

    // sequential LSTM (R6 structure: persistent W, flag signal + staged read)
    lstm_scan6<<<NBLK, 256, 0, stream>>>(gxp, Wfrag, c0, xbuf, flags, merged,
                                         out_h, out_c);

    // q = h_all @ W_att^T   [2048 x 1024]  (A = merged cols 0:512, lda=1536)
    gemm_bt<false, false, false, false, false, float>
        <<<dim3(8, 16), 256, 0, stream>>>(merged, 1536, W_att_h, 512, qbuf,
                                          1024, 512, nullptr, nullptr);

    // attention -> merged[:,512:1536]
    attn_apply<<<BT, 256, 0, stream>>>(qbuf, enc, merged);

    // outs = tanh(merged @ W_comb^T + b_comb)   [2048 x 512] f16
    gemm_bt<true, false, true, false, false, f16>
        <<<dim3(4, 16), 256, 0, stream>>>(merged, 1536, W_comb_h, 1536, outs_h,
                                          512, 1536, b_comb, nullptr);

    // logits = outs @ W_out^T + b_out   [2048 x 32000] fp32 -> d_out
    // MSWAP: m-tile on blockIdx.x so dispatch-adjacent blocks share W panel
    gemm_bt<true, false, false, false, true, float>
        <<<dim3(16, 250), 256, 0, stream>>>(outs_h, 512, W_out_h, 512,
                                            out_logits, V, 512, b_out,
                                            nullptr);
}